// Round 10
// baseline (146.576 us; speedup 1.0000x reference)
//
#include <hip/hip_runtime.h>
#include <math.h>

#define NODE_IN 64
#define NODE_OUT 96
#define EDGE_IN 16
#define EDGE_OUT 64
#define ACC_W 80          // NODE_IN + EDGE_IN
#define NB 500            // graphs
#define FPD 2048
#define FPE 128
#define XDIM 288          // 160 + 128
#define BN_EPS 1e-5f
#define HB 2048           // edges per hist/scatter block

// ---------------- K1: histogram + graph keys + edge-feature partial sums -----
// No global atomics. Per-block LDS: h[500] counts, facc[500][16] edge sums.
__global__ __launch_bounds__(512) void hist_kernel(
    const int* __restrict__ dst, const int* __restrict__ gids,
    const float* __restrict__ ef,
    int* __restrict__ gkey, int* __restrict__ pbh, float* __restrict__ pfe, int E)
{
    __shared__ int   h[NB];
    __shared__ float facc[NB * EDGE_IN];   // 32 KB
    const int t = threadIdx.x;
    for (int i = t; i < NB; i += 512) h[i] = 0;
    for (int i = t; i < NB * EDGE_IN; i += 512) facc[i] = 0.f;
    __syncthreads();

    const int lane = t & 63;
    const int w = t >> 6;                  // 8 waves
    const int q = lane >> 4, c = lane & 15;
    const int e0 = blockIdx.x * HB;

    for (int b = w; b < HB / 64; b += 8) {
        const int eb = e0 + b * 64;
        const int e = eb + lane;
        int g = -1;
        if (e < E) {
            g = gids[dst[e]];
            gkey[e] = g;
            atomicAdd(&h[g], 1);
        }
        // edge-feature accumulation: 4 edges x 16 cols per step, 8-deep pipeline
        // NOTE: idx is per-lane (depends on q) -> must use __shfl (bpermute),
        // NOT readlane (requires wave-uniform lane index; was the r9 bug).
        #pragma unroll
        for (int k0 = 0; k0 < 16; k0 += 8) {
            float v[8]; int gq[8];
            #pragma unroll
            for (int u = 0; u < 8; ++u) {
                const int idx = (k0 + u) * 4 + q;
                gq[u] = __shfl(g, idx);
                v[u] = (gq[u] >= 0) ? ef[(size_t)(eb + idx) * EDGE_IN + c] : 0.f;
            }
            #pragma unroll
            for (int u = 0; u < 8; ++u)
                if (gq[u] >= 0) atomicAdd(&facc[gq[u] * EDGE_IN + c], v[u]);
        }
    }
    __syncthreads();
    for (int i = t; i < NB; i += 512)
        pbh[(size_t)blockIdx.x * NB + i] = h[i];
    for (int i = t; i < NB * EDGE_IN; i += 512)
        pfe[(size_t)blockIdx.x * (NB * EDGE_IN) + i] = facc[i];
}

// ---------------- K2a: per-graph scan over blocks (500 blocks) ---------------
__global__ __launch_bounds__(256) void colscan_kernel(
    const int* __restrict__ pbh, int* __restrict__ pcs,
    int* __restrict__ gsum, int nblk)
{
    __shared__ int s[256];
    const int g = blockIdx.x;
    const int t = threadIdx.x;
    const int v0 = (t < nblk) ? pbh[(size_t)t * NB + g] : 0;
    s[t] = v0;
    __syncthreads();
    for (int d = 1; d < 256; d <<= 1) {
        const int v = (t >= d) ? s[t - d] : 0;
        __syncthreads();
        s[t] += v;
        __syncthreads();
    }
    if (t < nblk) pcs[(size_t)t * NB + g] = s[t] - v0;
    if (t == 255) gsum[g] = s[255];
}

// ---------------- K2b: scan over 500 graph totals ----------------------------
__global__ __launch_bounds__(512) void gscan_kernel(
    const int* __restrict__ gsum, int* __restrict__ offs, int* __restrict__ tot)
{
    __shared__ int s[512];
    const int t = threadIdx.x;
    const int v0 = (t < NB) ? gsum[t] : 0;
    s[t] = v0;
    __syncthreads();
    for (int d = 1; d < 512; d <<= 1) {
        const int v = (t >= d) ? s[t - d] : 0;
        __syncthreads();
        s[t] += v;
        __syncthreads();
    }
    if (t < NB) {
        offs[t] = s[t] - v0;
        tot[t]  = v0;
    }
}

// ---------------- K3: scatter src indices only (LDS-only atomics) ------------
__global__ __launch_bounds__(512) void scatter2_kernel(
    const int* __restrict__ gkey, const int* __restrict__ src,
    const int* __restrict__ pcs, const int* __restrict__ offs,
    int* __restrict__ ssrc, int E)
{
    __shared__ int h[NB];
    __shared__ int basel[NB];
    const int t = threadIdx.x;
    for (int i = t; i < NB; i += 512) {
        h[i] = 0;
        basel[i] = offs[i] + pcs[(size_t)blockIdx.x * NB + i];
    }
    __syncthreads();
    const int e0 = blockIdx.x * HB;
    #pragma unroll
    for (int i = 0; i < HB / 512; ++i) {
        const int e = e0 + i * 512 + t;
        if (e < E) {
            const int g = gkey[e];
            const int r = atomicAdd(&h[g], 1);
            ssrc[basel[g] + r] = src[e];
        }
    }
}

// ---------------- K4: fused graph-accum (blocks 0..499) + fp (blocks 500+) ---
__global__ __launch_bounds__(1024) void fused_kernel(
    const int* __restrict__ ssrc, const float* __restrict__ nf,
    const float* __restrict__ pfe, const int* __restrict__ offs,
    const int* __restrict__ tot, int nblk,
    const float* __restrict__ Wm, const float* __restrict__ bm,
    const float* __restrict__ We, const float* __restrict__ be,
    const float* __restrict__ fpv, const float* __restrict__ Wf,
    const float* __restrict__ bf, const float* __restrict__ gam,
    const float* __restrict__ bet, const float* __restrict__ mu,
    const float* __restrict__ var,
    float* __restrict__ xbuf, int E)
{
    __shared__ float sacc[16][NODE_IN];   // 4 KB
    __shared__ float epart[16][EDGE_IN];  // 1 KB
    __shared__ float accRow[ACC_W];
    __shared__ float red[1024];           // 4 KB
    __shared__ float part[7][4][FPE];     // 14 KB (fp path)

    const int t = threadIdx.x;

    if (blockIdx.x >= NB) {
        // ---------------- fingerprint encoder path ----------------
        const int j  = t & 127;
        const int kh = __builtin_amdgcn_readfirstlane(t >> 7);  // 0..7
        const int r0 = (blockIdx.x - NB) * 4;
        const int k0 = kh * 256;

        const float* __restrict__ xp0 = fpv + (size_t)(r0 + 0) * FPD + k0;
        const float* __restrict__ xp1 = fpv + (size_t)(r0 + 1) * FPD + k0;
        const float* __restrict__ xp2 = fpv + (size_t)(r0 + 2) * FPD + k0;
        const float* __restrict__ xp3 = fpv + (size_t)(r0 + 3) * FPD + k0;
        const float* __restrict__ wp  = Wf + (size_t)k0 * FPE + j;

        float a0 = 0.f, a1 = 0.f, a2 = 0.f, a3 = 0.f;
        for (int k = 0; k < 256; k += 8) {
            #pragma unroll
            for (int u = 0; u < 8; ++u) {
                const float w = wp[(size_t)(k + u) * FPE];
                a0 = fmaf(xp0[k + u], w, a0);
                a1 = fmaf(xp1[k + u], w, a1);
                a2 = fmaf(xp2[k + u], w, a2);
                a3 = fmaf(xp3[k + u], w, a3);
            }
        }
        if (kh > 0) {
            part[kh - 1][0][j] = a0; part[kh - 1][1][j] = a1;
            part[kh - 1][2][j] = a2; part[kh - 1][3][j] = a3;
        }
        __syncthreads();
        if (kh == 0) {
            #pragma unroll
            for (int qd = 0; qd < 7; ++qd) {
                a0 += part[qd][0][j]; a1 += part[qd][1][j];
                a2 += part[qd][2][j]; a3 += part[qd][3][j];
            }
            const float sc = rsqrtf(var[j] + BN_EPS) * gam[j];
            const float sh = bet[j] - mu[j] * sc;
            const float bj = bf[j];
            xbuf[(size_t)(r0 + 0) * XDIM + 160 + j] = fmaxf(fmaf(a0 + bj, sc, sh), 0.f);
            xbuf[(size_t)(r0 + 1) * XDIM + 160 + j] = fmaxf(fmaf(a1 + bj, sc, sh), 0.f);
            xbuf[(size_t)(r0 + 2) * XDIM + 160 + j] = fmaxf(fmaf(a2 + bj, sc, sh), 0.f);
            xbuf[(size_t)(r0 + 3) * XDIM + 160 + j] = fmaxf(fmaf(a3 + bj, sc, sh), 0.f);
        }
        return;
    }

    // ---------------- graph accumulation path ----------------
    const int g = blockIdx.x;
    const int lane = t & 63;
    const int w = t >> 6;            // 16 waves
    const int start = offs[g];
    const int cnt = tot[g];
    const int end = start + cnt;

    // edge-feature partial reduce (tiny): 16 cols x 16 chunks
    if (t < 256) {
        const int c = t & 15, ch = t >> 4;
        float s = 0.f;
        for (int b = ch; b < nblk; b += 16)
            s += pfe[(size_t)b * (NB * EDGE_IN) + g * EDGE_IN + c];
        epart[ch][c] = s;
    }

    // node gather: lane owns feature column `lane`, 16 loads in flight
    float nacc = 0.f;
    for (int p0 = start + w * 64; p0 < end; p0 += 1024) {
        const int lim = min(64, end - p0);
        const int sv = ssrc[min(p0 + lane, E - 1)];
        #pragma unroll
        for (int u0 = 0; u0 < 64; u0 += 16) {
            float v[16];
            #pragma unroll
            for (int u = 0; u < 16; ++u) {
                const int s = __builtin_amdgcn_readlane(sv, u0 + u);  // uniform idx
                v[u] = nf[(size_t)s * NODE_IN + lane];
            }
            #pragma unroll
            for (int u = 0; u < 16; ++u)
                nacc += (u0 + u < lim) ? v[u] : 0.f;
        }
    }
    sacc[w][lane] = nacc;
    __syncthreads();

    if (t < NODE_IN) {
        float s = 0.f;
        #pragma unroll
        for (int w2 = 0; w2 < 16; ++w2) s += sacc[w2][t];
        accRow[t] = s;
    } else if (t < ACC_W) {
        const int c = t - NODE_IN;
        float s = 0.f;
        #pragma unroll
        for (int ch = 0; ch < 16; ++ch) s += epart[ch][c];
        accRow[t] = s;
    }
    __syncthreads();

    // tiny GEMMs: [80] -> [160] molrow, plus count-scaled biases
    const float cntf = (float)cnt;
    float mr = 0.f;
    if (t < 96) {
        float m2 = 0.f;
        for (int k = 0; k < NODE_IN; ++k) m2 = fmaf(accRow[k], Wm[k * NODE_OUT + t], m2);
        mr = m2 + cntf * bm[t];
    } else if (t < 160) {
        const int j = t - 96;
        float m2 = 0.f;
        for (int k = 0; k < EDGE_IN; ++k) m2 = fmaf(accRow[NODE_IN + k], We[k * EDGE_OUT + j], m2);
        mr = m2 + cntf * be[j];
    }

    red[t] = (t < 160) ? mr : -1e30f;
    __syncthreads();
    for (int st = 512; st > 0; st >>= 1) {
        if (t < st) red[t] = fmaxf(red[t], red[t + st]);
        __syncthreads();
    }
    const float mx = red[0];
    __syncthreads();
    const float evx = (t < 160) ? expf(mr - mx) : 0.f;
    red[t] = evx;
    __syncthreads();
    for (int st = 512; st > 0; st >>= 1) {
        if (t < st) red[t] += red[t + st];
        __syncthreads();
    }
    if (t < 160) xbuf[(size_t)g * XDIM + t] = evx / red[0];
}

// ---------------- K5-K7: FFN, split-K in block --------------------------------
template<int NO, int KS>
__global__ __launch_bounds__(1024) void ffn_split(
    const float* __restrict__ X, const float* __restrict__ W,
    const float* __restrict__ bias, float* __restrict__ Y,
    int Bv, int Ni, int doRelu)
{
    __shared__ float part[KS - 1][4][NO];
    const int t = threadIdx.x;
    const int col = t % NO;
    const int ks = __builtin_amdgcn_readfirstlane(t / NO);
    const int r0 = blockIdx.x * 4;
    const int kchunk = Ni / KS;
    const int k0 = ks * kchunk;

    const float* __restrict__ xp0 = X + (size_t)(r0 + 0) * Ni + k0;
    const float* __restrict__ xp1 = X + (size_t)(r0 + 1) * Ni + k0;
    const float* __restrict__ xp2 = X + (size_t)(r0 + 2) * Ni + k0;
    const float* __restrict__ xp3 = X + (size_t)(r0 + 3) * Ni + k0;
    const float* __restrict__ wp  = W + (size_t)k0 * NO + col;

    float a0 = 0.f, a1 = 0.f, a2 = 0.f, a3 = 0.f;
    for (int k = 0; k < kchunk; k += 8) {
        #pragma unroll
        for (int u = 0; u < 8; ++u) {
            const float w = wp[(size_t)(k + u) * NO];
            a0 = fmaf(xp0[k + u], w, a0);
            a1 = fmaf(xp1[k + u], w, a1);
            a2 = fmaf(xp2[k + u], w, a2);
            a3 = fmaf(xp3[k + u], w, a3);
        }
    }
    if (ks > 0) {
        part[ks - 1][0][col] = a0; part[ks - 1][1][col] = a1;
        part[ks - 1][2][col] = a2; part[ks - 1][3][col] = a3;
    }
    __syncthreads();
    if (ks == 0) {
        #pragma unroll
        for (int qd = 0; qd < KS - 1; ++qd) {
            a0 += part[qd][0][col]; a1 += part[qd][1][col];
            a2 += part[qd][2][col]; a3 += part[qd][3][col];
        }
        const float bv = bias[col];
        float o0 = a0 + bv, o1 = a1 + bv, o2 = a2 + bv, o3 = a3 + bv;
        if (doRelu) {
            o0 = fmaxf(o0, 0.f); o1 = fmaxf(o1, 0.f);
            o2 = fmaxf(o2, 0.f); o3 = fmaxf(o3, 0.f);
        }
        Y[(size_t)(r0 + 0) * NO + col] = o0;
        if (r0 + 1 < Bv) Y[(size_t)(r0 + 1) * NO + col] = o1;
        if (r0 + 2 < Bv) Y[(size_t)(r0 + 2) * NO + col] = o2;
        if (r0 + 3 < Bv) Y[(size_t)(r0 + 3) * NO + col] = o3;
    }
}

extern "C" void kernel_launch(void* const* d_in, const int* in_sizes, int n_in,
                              void* d_out, int out_size, void* d_ws, size_t ws_size,
                              hipStream_t stream)
{
    const float* node_feats = (const float*)d_in[0];
    const float* edge_feats = (const float*)d_in[1];
    const float* fpv        = (const float*)d_in[2];
    const int*   src        = (const int*)d_in[3];
    const int*   dst        = (const int*)d_in[4];
    const int*   gids       = (const int*)d_in[5];
    const float* Wm  = (const float*)d_in[6];
    const float* bm  = (const float*)d_in[7];
    const float* We  = (const float*)d_in[8];
    const float* be  = (const float*)d_in[9];
    const float* Wf  = (const float*)d_in[10];
    const float* bf  = (const float*)d_in[11];
    const float* gam = (const float*)d_in[12];
    const float* bet = (const float*)d_in[13];
    const float* mu  = (const float*)d_in[14];
    const float* var = (const float*)d_in[15];
    const float* W0  = (const float*)d_in[16];
    const float* b0  = (const float*)d_in[17];
    const float* W1  = (const float*)d_in[18];
    const float* b1  = (const float*)d_in[19];
    const float* W2  = (const float*)d_in[20];
    const float* b2  = (const float*)d_in[21];
    const int E = in_sizes[3];
    const int nblk = (E + HB - 1) / HB;   // 245 for E=500000 (must be <= 256)

    // workspace layout
    float* xbuf  = (float*)d_ws;                          // [500][288]
    float* h1    = xbuf + (size_t)NB * XDIM;              // [500][512]
    float* h2    = h1 + (size_t)NB * 512;                 // [500][512]
    int*   gkey  = (int*)(h2 + (size_t)NB * 512);         // [E]
    int*   ssrc  = gkey + E;                               // [E]
    int*   pbh   = ssrc + E;                               // [nblk][NB]
    int*   pcs   = pbh + (size_t)nblk * NB;                // [nblk][NB]
    int*   gsum  = pcs + (size_t)nblk * NB;                // [NB]
    int*   offs  = gsum + NB;                              // [NB]
    int*   tot   = offs + NB;                              // [NB]
    float* pfe   = (float*)(tot + NB);                     // [nblk][NB][16]

    hipLaunchKernelGGL(hist_kernel, dim3(nblk), dim3(512), 0, stream,
                       dst, gids, edge_feats, gkey, pbh, pfe, E);
    hipLaunchKernelGGL(colscan_kernel, dim3(NB), dim3(256), 0, stream,
                       pbh, pcs, gsum, nblk);
    hipLaunchKernelGGL(gscan_kernel, dim3(1), dim3(512), 0, stream,
                       gsum, offs, tot);
    hipLaunchKernelGGL(scatter2_kernel, dim3(nblk), dim3(512), 0, stream,
                       gkey, src, pcs, offs, ssrc, E);
    hipLaunchKernelGGL(fused_kernel, dim3(NB + NB / 4), dim3(1024), 0, stream,
                       ssrc, node_feats, pfe, offs, tot, nblk,
                       Wm, bm, We, be,
                       fpv, Wf, bf, gam, bet, mu, var, xbuf, E);
    hipLaunchKernelGGL((ffn_split<512, 2>), dim3((NB + 3) / 4), dim3(1024), 0, stream,
                       xbuf, W0, b0, h1, NB, XDIM, 1);
    hipLaunchKernelGGL((ffn_split<512, 2>), dim3((NB + 3) / 4), dim3(1024), 0, stream,
                       h1, W1, b1, h2, NB, 512, 1);
    hipLaunchKernelGGL((ffn_split<256, 4>), dim3((NB + 3) / 4), dim3(1024), 0, stream,
                       h2, W2, b2, (float*)d_out, NB, 512, 0);
}

// Round 11
// 116.676 us; speedup vs baseline: 1.2563x; 1.2563x over previous
//
#include <hip/hip_runtime.h>
#include <math.h>

#define NODE_IN 64
#define NODE_OUT 96
#define EDGE_IN 16
#define EDGE_OUT 64
#define ACC_W 80          // NODE_IN + EDGE_IN
#define NB 500            // graphs
#define FPD 2048
#define FPE 128
#define XDIM 288          // 160 + 128
#define BN_EPS 1e-5f
#define HB 1024           // edges per hist/scatter block

// ---------------- K1: hist (blocks < nblk) + fingerprint encoder (rest) ------
// hist: 1 edge/thread, LDS count histogram, per-block flush. No global atomics.
// fp: 4 rows/block, 128 cols x 8 K-chunks, wave-uniform scalar X loads.
__global__ __launch_bounds__(1024) void hist_fp_kernel(
    const int* __restrict__ dst, const int* __restrict__ gids,
    int* __restrict__ gkey, int* __restrict__ pbh, int nblk,
    const float* __restrict__ fpv, const float* __restrict__ Wf,
    const float* __restrict__ bf, const float* __restrict__ gam,
    const float* __restrict__ bet, const float* __restrict__ mu,
    const float* __restrict__ var, float* __restrict__ xbuf, int E)
{
    __shared__ int   h[NB];
    __shared__ float part[7][4][FPE];     // fp path, 14 KB
    const int t = threadIdx.x;

    if (blockIdx.x >= nblk) {
        // ---------------- fingerprint encoder path ----------------
        const int j  = t & 127;
        const int kh = __builtin_amdgcn_readfirstlane(t >> 7);  // 0..7
        const int r0 = (blockIdx.x - nblk) * 4;
        const int k0 = kh * 256;

        const float* __restrict__ xp0 = fpv + (size_t)(r0 + 0) * FPD + k0;
        const float* __restrict__ xp1 = fpv + (size_t)(r0 + 1) * FPD + k0;
        const float* __restrict__ xp2 = fpv + (size_t)(r0 + 2) * FPD + k0;
        const float* __restrict__ xp3 = fpv + (size_t)(r0 + 3) * FPD + k0;
        const float* __restrict__ wp  = Wf + (size_t)k0 * FPE + j;

        float a0 = 0.f, a1 = 0.f, a2 = 0.f, a3 = 0.f;
        for (int k = 0; k < 256; k += 8) {
            #pragma unroll
            for (int u = 0; u < 8; ++u) {
                const float w = wp[(size_t)(k + u) * FPE];
                a0 = fmaf(xp0[k + u], w, a0);
                a1 = fmaf(xp1[k + u], w, a1);
                a2 = fmaf(xp2[k + u], w, a2);
                a3 = fmaf(xp3[k + u], w, a3);
            }
        }
        if (kh > 0) {
            part[kh - 1][0][j] = a0; part[kh - 1][1][j] = a1;
            part[kh - 1][2][j] = a2; part[kh - 1][3][j] = a3;
        }
        __syncthreads();
        if (kh == 0) {
            #pragma unroll
            for (int qd = 0; qd < 7; ++qd) {
                a0 += part[qd][0][j]; a1 += part[qd][1][j];
                a2 += part[qd][2][j]; a3 += part[qd][3][j];
            }
            const float sc = rsqrtf(var[j] + BN_EPS) * gam[j];
            const float sh = bet[j] - mu[j] * sc;
            const float bj = bf[j];
            xbuf[(size_t)(r0 + 0) * XDIM + 160 + j] = fmaxf(fmaf(a0 + bj, sc, sh), 0.f);
            xbuf[(size_t)(r0 + 1) * XDIM + 160 + j] = fmaxf(fmaf(a1 + bj, sc, sh), 0.f);
            xbuf[(size_t)(r0 + 2) * XDIM + 160 + j] = fmaxf(fmaf(a2 + bj, sc, sh), 0.f);
            xbuf[(size_t)(r0 + 3) * XDIM + 160 + j] = fmaxf(fmaf(a3 + bj, sc, sh), 0.f);
        }
        return;
    }

    // ---------------- histogram path ----------------
    for (int i = t; i < NB; i += 1024) h[i] = 0;
    __syncthreads();
    const int e = blockIdx.x * HB + t;
    if (e < E) {
        const int g = gids[dst[e]];
        gkey[e] = g;
        atomicAdd(&h[g], 1);
    }
    __syncthreads();
    for (int i = t; i < NB; i += 1024)
        pbh[(size_t)blockIdx.x * NB + i] = h[i];
}

// ---------------- K2a: per-graph scan over blocks (500 blocks) ---------------
__global__ __launch_bounds__(512) void colscan_kernel(
    const int* __restrict__ pbh, int* __restrict__ pcs,
    int* __restrict__ gsum, int nblk)
{
    __shared__ int s[512];
    const int g = blockIdx.x;
    const int t = threadIdx.x;
    const int v0 = (t < nblk) ? pbh[(size_t)t * NB + g] : 0;
    s[t] = v0;
    __syncthreads();
    for (int d = 1; d < 512; d <<= 1) {
        const int v = (t >= d) ? s[t - d] : 0;
        __syncthreads();
        s[t] += v;
        __syncthreads();
    }
    if (t < nblk) pcs[(size_t)t * NB + g] = s[t] - v0;
    if (t == 511) gsum[g] = s[511];
}

// ---------------- K2b: scan over 500 graph totals ----------------------------
__global__ __launch_bounds__(512) void gscan_kernel(
    const int* __restrict__ gsum, int* __restrict__ offs, int* __restrict__ tot)
{
    __shared__ int s[512];
    const int t = threadIdx.x;
    const int v0 = (t < NB) ? gsum[t] : 0;
    s[t] = v0;
    __syncthreads();
    for (int d = 1; d < 512; d <<= 1) {
        const int v = (t >= d) ? s[t - d] : 0;
        __syncthreads();
        s[t] += v;
        __syncthreads();
    }
    if (t < NB) {
        offs[t] = s[t] - v0;
        tot[t]  = v0;
    }
}

// ---------------- K3: scatter src + edge id (LDS-only atomics) ---------------
__global__ __launch_bounds__(1024) void scatter2_kernel(
    const int* __restrict__ gkey, const int* __restrict__ src,
    const int* __restrict__ pcs, const int* __restrict__ offs,
    int* __restrict__ ssrc, int* __restrict__ seid, int E)
{
    __shared__ int h[NB];
    __shared__ int basel[NB];
    const int t = threadIdx.x;
    for (int i = t; i < NB; i += 1024) {
        h[i] = 0;
        basel[i] = offs[i] + pcs[(size_t)blockIdx.x * NB + i];
    }
    __syncthreads();
    const int e = blockIdx.x * HB + t;
    if (e < E) {
        const int g = gkey[e];
        const int r = atomicAdd(&h[g], 1);
        const int p = basel[g] + r;
        ssrc[p] = src[e];
        seid[p] = e;
    }
}

// ---------------- K4: per-graph accumulation + mol GEMM + softmax ------------
__global__ __launch_bounds__(1024) void graph_accum(
    const int* __restrict__ ssrc, const int* __restrict__ seid,
    const float* __restrict__ nf, const float* __restrict__ ef,
    const int* __restrict__ offs, const int* __restrict__ tot,
    const float* __restrict__ Wm, const float* __restrict__ bm,
    const float* __restrict__ We, const float* __restrict__ be,
    float* __restrict__ xbuf, int E)
{
    const int g = blockIdx.x;
    const int t = threadIdx.x;
    const int lane = t & 63;
    const int w = t >> 6;            // 16 waves
    const int start = offs[g];
    const int cnt = tot[g];
    const int end = start + cnt;
    const int q = lane >> 4, c = lane & 15;

    __shared__ float sacc[16][ACC_W];
    __shared__ float accRow[ACC_W];
    __shared__ float red[1024];

    float nacc = 0.f;   // node part: lane owns feature column `lane`
    float eacc = 0.f;   // edge part: column c, quarter q

    for (int p0 = start + w * 64; p0 < end; p0 += 1024) {
        const int lim = min(64, end - p0);
        const int sv = ssrc[min(p0 + lane, E - 1)];
        const int ev = seid[min(p0 + lane, E - 1)];

        // node rows: 16 independent gather loads in flight (uniform readlane idx)
        #pragma unroll
        for (int u0 = 0; u0 < 64; u0 += 16) {
            float v[16];
            #pragma unroll
            for (int u = 0; u < 16; ++u) {
                const int s = __builtin_amdgcn_readlane(sv, u0 + u);
                v[u] = nf[(size_t)s * NODE_IN + lane];
            }
            #pragma unroll
            for (int u = 0; u < 16; ++u)
                nacc += (u0 + u < lim) ? v[u] : 0.f;
        }

        // edge rows: 4 edges x 16 cols per step, 8-deep; divergent idx -> __shfl
        #pragma unroll
        for (int u0 = 0; u0 < 16; u0 += 8) {
            float w8[8];
            int idx8[8];
            #pragma unroll
            for (int u = 0; u < 8; ++u) {
                const int idx = (u0 + u) * 4 + q;
                const int eid = __shfl(ev, idx);
                idx8[u] = idx;
                w8[u] = ef[(size_t)eid * EDGE_IN + c];
            }
            #pragma unroll
            for (int u = 0; u < 8; ++u)
                eacc += (idx8[u] < lim) ? w8[u] : 0.f;
        }
    }

    sacc[w][lane] = nacc;          // lanes 0..63 hold node cols
    eacc += __shfl_xor(eacc, 16);
    eacc += __shfl_xor(eacc, 32);
    if (lane < EDGE_IN) sacc[w][NODE_IN + lane] = eacc;
    __syncthreads();
    if (t < ACC_W) {
        float s = 0.f;
        #pragma unroll
        for (int w2 = 0; w2 < 16; ++w2) s += sacc[w2][t];
        accRow[t] = s;
    }
    __syncthreads();

    // tiny GEMMs: [80] -> [160] molrow, plus count-scaled biases
    const float cntf = (float)cnt;
    float mr = 0.f;
    if (t < 96) {
        float m2 = 0.f;
        for (int k = 0; k < NODE_IN; ++k) m2 = fmaf(accRow[k], Wm[k * NODE_OUT + t], m2);
        mr = m2 + cntf * bm[t];
    } else if (t < 160) {
        const int j = t - 96;
        float m2 = 0.f;
        for (int k = 0; k < EDGE_IN; ++k) m2 = fmaf(accRow[NODE_IN + k], We[k * EDGE_OUT + j], m2);
        mr = m2 + cntf * be[j];
    }

    red[t] = (t < 160) ? mr : -1e30f;
    __syncthreads();
    for (int st = 512; st > 0; st >>= 1) {
        if (t < st) red[t] = fmaxf(red[t], red[t + st]);
        __syncthreads();
    }
    const float mx = red[0];
    __syncthreads();
    const float evx = (t < 160) ? expf(mr - mx) : 0.f;
    red[t] = evx;
    __syncthreads();
    for (int st = 512; st > 0; st >>= 1) {
        if (t < st) red[t] += red[t + st];
        __syncthreads();
    }
    if (t < 160) xbuf[(size_t)g * XDIM + t] = evx / red[0];
}

// ---------------- K5-K7: FFN, split-K in block --------------------------------
template<int NO, int KS>
__global__ __launch_bounds__(1024) void ffn_split(
    const float* __restrict__ X, const float* __restrict__ W,
    const float* __restrict__ bias, float* __restrict__ Y,
    int Bv, int Ni, int doRelu)
{
    __shared__ float part[KS - 1][4][NO];
    const int t = threadIdx.x;
    const int col = t % NO;
    const int ks = __builtin_amdgcn_readfirstlane(t / NO);
    const int r0 = blockIdx.x * 4;
    const int kchunk = Ni / KS;
    const int k0 = ks * kchunk;

    const float* __restrict__ xp0 = X + (size_t)(r0 + 0) * Ni + k0;
    const float* __restrict__ xp1 = X + (size_t)(r0 + 1) * Ni + k0;
    const float* __restrict__ xp2 = X + (size_t)(r0 + 2) * Ni + k0;
    const float* __restrict__ xp3 = X + (size_t)(r0 + 3) * Ni + k0;
    const float* __restrict__ wp  = W + (size_t)k0 * NO + col;

    float a0 = 0.f, a1 = 0.f, a2 = 0.f, a3 = 0.f;
    for (int k = 0; k < kchunk; k += 8) {
        #pragma unroll
        for (int u = 0; u < 8; ++u) {
            const float w = wp[(size_t)(k + u) * NO];
            a0 = fmaf(xp0[k + u], w, a0);
            a1 = fmaf(xp1[k + u], w, a1);
            a2 = fmaf(xp2[k + u], w, a2);
            a3 = fmaf(xp3[k + u], w, a3);
        }
    }
    if (ks > 0) {
        part[ks - 1][0][col] = a0; part[ks - 1][1][col] = a1;
        part[ks - 1][2][col] = a2; part[ks - 1][3][col] = a3;
    }
    __syncthreads();
    if (ks == 0) {
        #pragma unroll
        for (int qd = 0; qd < KS - 1; ++qd) {
            a0 += part[qd][0][col]; a1 += part[qd][1][col];
            a2 += part[qd][2][col]; a3 += part[qd][3][col];
        }
        const float bv = bias[col];
        float o0 = a0 + bv, o1 = a1 + bv, o2 = a2 + bv, o3 = a3 + bv;
        if (doRelu) {
            o0 = fmaxf(o0, 0.f); o1 = fmaxf(o1, 0.f);
            o2 = fmaxf(o2, 0.f); o3 = fmaxf(o3, 0.f);
        }
        Y[(size_t)(r0 + 0) * NO + col] = o0;
        if (r0 + 1 < Bv) Y[(size_t)(r0 + 1) * NO + col] = o1;
        if (r0 + 2 < Bv) Y[(size_t)(r0 + 2) * NO + col] = o2;
        if (r0 + 3 < Bv) Y[(size_t)(r0 + 3) * NO + col] = o3;
    }
}

extern "C" void kernel_launch(void* const* d_in, const int* in_sizes, int n_in,
                              void* d_out, int out_size, void* d_ws, size_t ws_size,
                              hipStream_t stream)
{
    const float* node_feats = (const float*)d_in[0];
    const float* edge_feats = (const float*)d_in[1];
    const float* fpv        = (const float*)d_in[2];
    const int*   src        = (const int*)d_in[3];
    const int*   dst        = (const int*)d_in[4];
    const int*   gids       = (const int*)d_in[5];
    const float* Wm  = (const float*)d_in[6];
    const float* bm  = (const float*)d_in[7];
    const float* We  = (const float*)d_in[8];
    const float* be  = (const float*)d_in[9];
    const float* Wf  = (const float*)d_in[10];
    const float* bf  = (const float*)d_in[11];
    const float* gam = (const float*)d_in[12];
    const float* bet = (const float*)d_in[13];
    const float* mu  = (const float*)d_in[14];
    const float* var = (const float*)d_in[15];
    const float* W0  = (const float*)d_in[16];
    const float* b0  = (const float*)d_in[17];
    const float* W1  = (const float*)d_in[18];
    const float* b1  = (const float*)d_in[19];
    const float* W2  = (const float*)d_in[20];
    const float* b2  = (const float*)d_in[21];
    const int E = in_sizes[3];
    const int nblk = (E + HB - 1) / HB;   // 489 for E=500000 (must be <= 512)

    // workspace layout
    float* xbuf  = (float*)d_ws;                          // [500][288]
    float* h1    = xbuf + (size_t)NB * XDIM;              // [500][512]
    float* h2    = h1 + (size_t)NB * 512;                 // [500][512]
    int*   gkey  = (int*)(h2 + (size_t)NB * 512);         // [E]
    int*   ssrc  = gkey + E;                               // [E]
    int*   seid  = ssrc + E;                               // [E]
    int*   pbh   = seid + E;                               // [nblk][NB]
    int*   pcs   = pbh + (size_t)nblk * NB;                // [nblk][NB]
    int*   gsum  = pcs + (size_t)nblk * NB;                // [NB]
    int*   offs  = gsum + NB;                              // [NB]
    int*   tot   = offs + NB;                              // [NB]

    hipLaunchKernelGGL(hist_fp_kernel, dim3(nblk + NB / 4), dim3(1024), 0, stream,
                       dst, gids, gkey, pbh, nblk,
                       fpv, Wf, bf, gam, bet, mu, var, xbuf, E);
    hipLaunchKernelGGL(colscan_kernel, dim3(NB), dim3(512), 0, stream,
                       pbh, pcs, gsum, nblk);
    hipLaunchKernelGGL(gscan_kernel, dim3(1), dim3(512), 0, stream,
                       gsum, offs, tot);
    hipLaunchKernelGGL(scatter2_kernel, dim3(nblk), dim3(1024), 0, stream,
                       gkey, src, pcs, offs, ssrc, seid, E);
    hipLaunchKernelGGL(graph_accum, dim3(NB), dim3(1024), 0, stream,
                       ssrc, seid, node_feats, edge_feats, offs, tot,
                       Wm, bm, We, be, xbuf, E);
    hipLaunchKernelGGL((ffn_split<512, 2>), dim3((NB + 3) / 4), dim3(1024), 0, stream,
                       xbuf, W0, b0, h1, NB, XDIM, 1);
    hipLaunchKernelGGL((ffn_split<512, 2>), dim3((NB + 3) / 4), dim3(1024), 0, stream,
                       h1, W1, b1, h2, NB, 512, 1);
    hipLaunchKernelGGL((ffn_split<256, 4>), dim3((NB + 3) / 4), dim3(1024), 0, stream,
                       h2, W2, b2, (float*)d_out, NB, 512, 0);
}